// Round 1
// baseline (106.650 us; speedup 1.0000x reference)
//
#include <hip/hip_runtime.h>

// Problem constants (fixed by setup_inputs)
constexpr int N_ = 1024, K_ = 64, D_ = 9, E_ = 10;
constexpr int A1_ = 3, A2_ = 8, A3_ = 18, A_ = 29;
constexpr int NP2 = 45;   // sorted pairs (i<=j) of 9
constexpr int NP3 = 165;  // sorted triples (i<=j<=l) of 9

// Workspace layout (float offsets)
constexpr int OFF_WP  = 0;                        // E*A*K      = 18560
constexpr int OFF_U3S = OFF_WP  + E_*A_*K_;       // NP3*D*A3   = 26730
constexpr int OFF_U2S = OFF_U3S + NP3*D_*A3_;     // NP2*D*A2   = 3240
constexpr int OFF_S3  = OFF_U2S + NP2*D_*A2_;     // E*K*NP3*D  = 950400
constexpr int OFF_S2  = OFF_S3  + E_*K_*NP3*D_;   // E*K*NP2*D  = 259200
constexpr int OFF_C1  = OFF_S2  + E_*K_*NP2*D_;   // E*K*D*D    = 51840
constexpr int WS_FLOATS = OFF_C1 + E_*K_*D_*D_;   // ~1.31M floats = 5.24 MB

// ---------------------------------------------------------------------------
// Kernel 1: wp = einsum('zak,ab->zbk', w, proj); symmetrize U3 -> U3S[t][o][m],
//           U2 -> U2S[p][o][m]. One-time prep, disjoint output ranges by tid.
// ---------------------------------------------------------------------------
__global__ void prep_kernel(const float* __restrict__ w,
                            const float* __restrict__ proj,
                            const float* __restrict__ U2,
                            const float* __restrict__ U3,
                            float* __restrict__ ws) {
  const int WP_N  = E_*A_*K_;
  const int U3S_N = NP3*D_*A3_;
  const int U2S_N = NP2*D_*A2_;
  int idx = blockIdx.x * blockDim.x + threadIdx.x;
  if (idx < WP_N) {
    int e = idx / (A_*K_); int r = idx % (A_*K_); int b = r / K_; int k = r % K_;
    float acc = 0.f;
    for (int a = 0; a < A_; ++a)
      acc = fmaf(w[(e*A_ + a)*K_ + k], proj[a*A_ + b], acc);
    ws[OFF_WP + idx] = acc;
  } else if (idx < WP_N + U3S_N) {
    int id = idx - WP_N;
    int t = id / (D_*A3_); int r = id % (D_*A3_); int o = r / A3_; int m = r % A3_;
    // decode sorted triple index t -> (i<=j<=l)
    int ti = 0, tj = 0, tl = 0, c = 0;
    for (int a = 0; a < D_; ++a)
      for (int b = a; b < D_; ++b)
        for (int g = b; g < D_; ++g) { if (c == t) { ti = a; tj = b; tl = g; } ++c; }
    auto u3 = [&](int a, int b, int g) {
      return U3[(((o*D_ + a)*D_ + b)*D_ + g)*A3_ + m];
    };
    float s;
    if (ti == tj && tj == tl)      s = u3(ti, ti, ti);
    else if (ti == tj)             s = u3(ti, ti, tl) + u3(ti, tl, ti) + u3(tl, ti, ti);
    else if (tj == tl)             s = u3(ti, tj, tj) + u3(tj, ti, tj) + u3(tj, tj, ti);
    else                           s = u3(ti, tj, tl) + u3(ti, tl, tj) + u3(tj, ti, tl)
                                     + u3(tj, tl, ti) + u3(tl, ti, tj) + u3(tl, tj, ti);
    ws[OFF_U3S + id] = s;   // [t][o][m]
  } else if (idx < WP_N + U3S_N + U2S_N) {
    int id = idx - WP_N - U3S_N;
    int p = id / (D_*A2_); int r = id % (D_*A2_); int o = r / A2_; int m = r % A2_;
    int pi = 0, pj = 0, c = 0;
    for (int a = 0; a < D_; ++a)
      for (int b = a; b < D_; ++b) { if (c == p) { pi = a; pj = b; } ++c; }
    float s = U2[((o*D_ + pi)*D_ + pj)*A2_ + m];
    if (pi != pj) s += U2[((o*D_ + pj)*D_ + pi)*A2_ + m];
    ws[OFF_U2S + id] = s;   // [p][o][m]
  }
}

// ---------------------------------------------------------------------------
// Kernel 2: per (e,k): S3[t][o] = sum_m U3S[t][o][m]*w3[m]
//                      S2[p][o] = sum_m U2S[p][o][m]*w2[m]
//                      C1[i][o] = sum_m U1[o][i][m]*w1[m]
// ---------------------------------------------------------------------------
__global__ void weights_kernel(const float* __restrict__ U1,
                               float* __restrict__ ws) {
  int ek = blockIdx.x;            // e*K + k
  int e = ek / K_, k = ek % K_;
  __shared__ float wpk[A_];
  if (threadIdx.x < A_)
    wpk[threadIdx.x] = ws[OFF_WP + (e*A_ + threadIdx.x)*K_ + k];
  __syncthreads();
  const float* u3s = ws + OFF_U3S;
  const float* u2s = ws + OFF_U2S;
  float* s3 = ws + OFF_S3 + ek*(NP3*D_);
  float* s2 = ws + OFF_S2 + ek*(NP2*D_);
  float* c1 = ws + OFF_C1 + ek*(D_*D_);
  const int TOT = NP3*D_ + NP2*D_ + D_*D_;   // 1485 + 405 + 81 = 1971
  for (int idx = threadIdx.x; idx < TOT; idx += blockDim.x) {
    if (idx < NP3*D_) {
      int t = idx / D_, o = idx % D_;
      float acc = 0.f;
      #pragma unroll
      for (int m = 0; m < A3_; ++m)
        acc = fmaf(u3s[(t*D_ + o)*A3_ + m], wpk[A1_ + A2_ + m], acc);
      s3[t*D_ + o] = acc;
    } else if (idx < NP3*D_ + NP2*D_) {
      int id = idx - NP3*D_;
      int p = id / D_, o = id % D_;
      float acc = 0.f;
      #pragma unroll
      for (int m = 0; m < A2_; ++m)
        acc = fmaf(u2s[(p*D_ + o)*A2_ + m], wpk[A1_ + m], acc);
      s2[p*D_ + o] = acc;
    } else {
      int id = idx - NP3*D_ - NP2*D_;
      int i = id / D_, o = id % D_;
      float acc = 0.f;
      #pragma unroll
      for (int m = 0; m < A1_; ++m)
        acc = fmaf(U1[(o*D_ + i)*A1_ + m], wpk[m], acc);
      c1[i*D_ + o] = acc;
    }
  }
}

// ---------------------------------------------------------------------------
// Kernel 3: main. Block = one (e,k); thread = one n of that species.
// All S3/S2/C1 reads are wave-uniform -> scalar loads (SGPR broadcast).
// out[o] = sum_i x_i*(C1[o,i] + sum_j x_j*(C2[o,i,j] + sum_l x_l*T3[o,i,j,l]))
//        = sum_i C1 x_i + sum_{p=(i<=j)} S2[p] x_i x_j + sum_{t=(i<=j<=l)} S3[t] x_i x_j x_l
// ---------------------------------------------------------------------------
__global__ __launch_bounds__(128) void main_kernel(const float* __restrict__ x,
                                                   const int* __restrict__ counts,
                                                   const float* __restrict__ ws,
                                                   float* __restrict__ out) {
  int ek = blockIdx.x;
  int e = ek / K_, k = ek % K_;
  int start = 0;
  for (int s = 0; s < e; ++s) start += counts[s];
  int cnt = counts[e];
  int tid = threadIdx.x;
  bool active = tid < cnt;
  int n = start + tid;
  int nc = active ? n : start;            // clamp for safe OOB-free loads
  const float* xp = x + (nc*K_ + k)*D_;
  float xv[D_];
  #pragma unroll
  for (int l = 0; l < D_; ++l) xv[l] = xp[l];

  const float* s3 = ws + OFF_S3 + ek*(NP3*D_);
  const float* s2 = ws + OFF_S2 + ek*(NP2*D_);
  const float* c1 = ws + OFF_C1 + ek*(D_*D_);

  float acc[D_];
  #pragma unroll
  for (int o = 0; o < D_; ++o) acc[o] = 0.f;

  int t = 0, p = 0;
  #pragma unroll
  for (int i = 0; i < D_; ++i) {
    float xi = xv[i];
    #pragma unroll
    for (int o = 0; o < D_; ++o) acc[o] = fmaf(c1[i*D_ + o], xi, acc[o]);
    #pragma unroll
    for (int j = i; j < D_; ++j) {
      float xij = xi * xv[j];
      #pragma unroll
      for (int o = 0; o < D_; ++o) acc[o] = fmaf(s2[p*D_ + o], xij, acc[o]);
      ++p;
      #pragma unroll
      for (int l = j; l < D_; ++l) {
        float xijl = xij * xv[l];
        #pragma unroll
        for (int o = 0; o < D_; ++o) acc[o] = fmaf(s3[t*D_ + o], xijl, acc[o]);
        ++t;
      }
    }
  }

  if (active) {
    float* op = out + (n*K_ + k)*D_;
    #pragma unroll
    for (int o = 0; o < D_; ++o) op[o] = acc[o];
  }
}

// ---------------------------------------------------------------------------
extern "C" void kernel_launch(void* const* d_in, const int* in_sizes, int n_in,
                              void* d_out, int out_size, void* d_ws, size_t ws_size,
                              hipStream_t stream) {
  const float* x     = (const float*)d_in[0];
  const int*   cnts  = (const int*)  d_in[1];
  const float* w     = (const float*)d_in[2];
  const float* proj  = (const float*)d_in[3];
  const float* U1    = (const float*)d_in[4];
  const float* U2    = (const float*)d_in[5];
  const float* U3    = (const float*)d_in[6];
  float* out = (float*)d_out;
  float* ws  = (float*)d_ws;   // needs WS_FLOATS*4 ~= 5.3 MB

  const int PREP_N = E_*A_*K_ + NP3*D_*A3_ + NP2*D_*A2_;   // 48530
  int prep_blocks = (PREP_N + 255) / 256;
  prep_kernel<<<prep_blocks, 256, 0, stream>>>(w, proj, U2, U3, ws);
  weights_kernel<<<E_*K_, 256, 0, stream>>>(U1, ws);
  main_kernel<<<E_*K_, 128, 0, stream>>>(x, cnts, ws, out);
}